// Round 10
// baseline (867.602 us; speedup 1.0000x reference)
//
#include <hip/hip_runtime.h>

#define B_ 256
#define T_ 512
#define F_ 64
#define U_ 128
#define BPB 16   // batches per block
#define HC 16    // steps per half-chunk

typedef _Float16 f16x8 __attribute__((ext_vector_type(8)));
typedef float f32x4 __attribute__((ext_vector_type(4)));
typedef _Float16 h2v __attribute__((ext_vector_type(2)));
union U32H2 { unsigned u; h2v h; };

__device__ __forceinline__ unsigned packh2(float a, float b) {
  U32H2 r; r.h[0] = (_Float16)a; r.h[1] = (_Float16)b; return r.u;
}
__device__ __forceinline__ float fast_sig(float x) {
  return __builtin_amdgcn_rcpf(1.0f + __expf(-x));
}
__device__ __forceinline__ float fast_tanh(float x) {
  return fmaf(-2.0f, __builtin_amdgcn_rcpf(1.0f + __expf(2.0f * x)), 1.0f);
}
#define MFMA(a, b, c) __builtin_amdgcn_mfma_f32_16x16x32_f16((a), (b), (c), 0, 0, 0)

__global__ __launch_bounds__(256, 1)
__attribute__((amdgpu_waves_per_eu(1, 1)))
void grud_kernel(
    const float* __restrict__ x, const float* __restrict__ m,
    const float* __restrict__ delta_t,
    const float* __restrict__ Wz_, const float* __restrict__ Uz, const float* __restrict__ bz,
    const float* __restrict__ Wr_, const float* __restrict__ Ur, const float* __restrict__ br,
    const float* __restrict__ Wh_, const float* __restrict__ Uh, const float* __restrict__ bh,
    const float* __restrict__ gxd, const float* __restrict__ ghd,
    const float* __restrict__ mi,
    float* __restrict__ out)
{
  const int tid = threadIdx.x;
  const int w   = tid >> 6;          // wave 0..3: owns col tiles 2w, 2w+1
  const int l   = tid & 63;
  const int bl  = l & 15;            // lane's batch (N-dim of D', n = l&15)
  const int g   = l >> 4;            // lane quarter
  const int bg  = blockIdx.x * BPB;  // batch group base

  __shared__ ushort s_x[HC * 16 * 64];      // decayed x fp16, swizzled  (32KB)
  __shared__ ushort s_hist[HC * 16 * 128];  // outputs fp16, swizzled    (64KB)
  __shared__ ushort s_hd[16 * 128];         // h_dec fp16, swizzled      (4KB)
  __shared__ ushort s_rh[16 * 128];         // r*h_dec fp16, swizzled    (4KB)
  __shared__ float  s_dtn[HC * 16];         // dt[t+1] per (tc, batch)   (1KB)

  // ---- weight A-fragments: A'[m=col][k], element j = U[32kc+8g+j][colbase+bl] ----
  f16x8 uzA[2][4], urA[2][4], uhA[2][4];
  f16x8 wzA[2][2], wrA[2][2], whA[2][2];
#pragma unroll
  for (int q = 0; q < 2; ++q) {
    const int cq = 32 * w + 16 * q + bl;
#pragma unroll
    for (int kc = 0; kc < 4; ++kc) {
#pragma unroll
      for (int j = 0; j < 8; ++j) {
        const int k = 32 * kc + 8 * g + j;
        uzA[q][kc][j] = (_Float16)Uz[k * U_ + cq];
        urA[q][kc][j] = (_Float16)Ur[k * U_ + cq];
        uhA[q][kc][j] = (_Float16)Uh[k * U_ + cq];
      }
    }
#pragma unroll
    for (int kc = 0; kc < 2; ++kc) {
#pragma unroll
      for (int j = 0; j < 8; ++j) {
        const int f = 32 * kc + 8 * g + j;
        wzA[q][kc][j] = (_Float16)Wz_[f * U_ + cq];
        wrA[q][kc][j] = (_Float16)Wr_[f * U_ + cq];
        whA[q][kc][j] = (_Float16)Wh_[f * U_ + cq];
      }
    }
  }
  // per-lane column scalars (D' row = col = 32w + 16q + 4g + r)
  f32x4 bzF[2], brF[2], bhF[2];
  float gam[2][4];
#pragma unroll
  for (int q = 0; q < 2; ++q)
#pragma unroll
    for (int r = 0; r < 4; ++r) {
      const int col = 32 * w + 16 * q + 4 * g + r;
      bzF[q][r] = bz[col]; brF[q][r] = br[col]; bhF[q][r] = bh[col];
      gam[q][r] = -fmaxf(ghd[col], 0.0f);
    }
  // x staging constants: this thread always handles features f0, f0+1
  const int f0 = 2 * (tid & 31);
  const float gx0 = -fmaxf(gxd[f0], 0.0f), gx1 = -fmaxf(gxd[f0 + 1], 0.0f);
  const float mi0 = mi[f0], mi1 = mi[f0 + 1];

  // zero h_dec (h0 = 0)
#pragma unroll
  for (int i = 0; i < 8; ++i) s_hd[tid * 8 + i] = 0;

  f32x4 hdT[2];
  hdT[0] = (f32x4){0.f, 0.f, 0.f, 0.f};
  hdT[1] = (f32x4){0.f, 0.f, 0.f, 0.f};
  f32x4 axz[2], axr[2], axh[2];
  float zz[2][4], ghn[2][4];

  // swizzled write offsets (ushort units) for this lane's 4-col groups
  const int c00 = 32 * w + 4 * g;
  const int c01 = c00 + 16;
  const int hw0 = bl * 128 + (((c00 >> 3) ^ (bl & 7)) << 3) + (c00 & 7);
  const int hw1 = bl * 128 + (((c01 >> 3) ^ (bl & 7)) << 3) + (c01 & 7);

#define AXLOAD(T) do {                                                        \
    const int xo = (T) * 1024 + bl * 64;                                      \
    const f16x8 xb0 = *(const f16x8*)(s_x + xo + (((0 + g) ^ (bl & 7)) << 3));\
    const f16x8 xb1 = *(const f16x8*)(s_x + xo + (((4 + g) ^ (bl & 7)) << 3));\
    axz[0] = bzF[0]; axz[1] = bzF[1];                                         \
    axr[0] = brF[0]; axr[1] = brF[1];                                         \
    axh[0] = bhF[0]; axh[1] = bhF[1];                                         \
    axz[0] = MFMA(wzA[0][0], xb0, axz[0]); axz[0] = MFMA(wzA[0][1], xb1, axz[0]); \
    axz[1] = MFMA(wzA[1][0], xb0, axz[1]); axz[1] = MFMA(wzA[1][1], xb1, axz[1]); \
    axr[0] = MFMA(wrA[0][0], xb0, axr[0]); axr[0] = MFMA(wrA[0][1], xb1, axr[0]); \
    axr[1] = MFMA(wrA[1][0], xb0, axr[1]); axr[1] = MFMA(wrA[1][1], xb1, axr[1]); \
    axh[0] = MFMA(whA[0][0], xb0, axh[0]); axh[0] = MFMA(whA[0][1], xb1, axh[0]); \
    axh[1] = MFMA(whA[1][0], xb0, axh[1]); axh[1] = MFMA(whA[1][1], xb1, axh[1]); \
  } while (0)

#pragma unroll 1
  for (int hc = 0; hc < T_ / HC; ++hc) {
    const int t0 = hc * HC;
    __syncthreads();

    // ---- flush previous half-chunk outputs (coalesced, bulk) ----
    if (hc > 0) {
      const int t0p = t0 - HC;
#pragma unroll 1
      for (int i = 0; i < 16; ++i) {
        const int e = tid + 256 * i;
        const int ck = e & 15, b = (e >> 4) & 15, t = e >> 8;
        const int pck = (ck & 8) | ((ck ^ b) & 7);
        const f16x8 hv = *(const f16x8*)(s_hist + t * 2048 + b * 128 + pck * 8);
        float4 o0, o1;
        o0.x = (float)hv[0]; o0.y = (float)hv[1]; o0.z = (float)hv[2]; o0.w = (float)hv[3];
        o1.x = (float)hv[4]; o1.y = (float)hv[5]; o1.z = (float)hv[6]; o1.w = (float)hv[7];
        float* ob = out + ((size_t)(bg + b) * T_ + t0p + t) * U_ + ck * 8;
        *(float4*)ob = o0; *(float4*)(ob + 4) = o1;
      }
    }
    // ---- stage dt_next table ----
    {
      const int tcs = tid >> 4, bs = tid & 15;
      const int tt = t0 + tcs + 1;
      s_dtn[tcs * 16 + bs] = (tt < T_) ? delta_t[(size_t)(bg + bs) * T_ + tt] : 0.0f;
    }
    // ---- stage decayed x (fp16, swizzled) ----
#pragma unroll 1
    for (int i = 0; i < 32; ++i) {
      const int e = tid + 256 * i;
      const int b = (e >> 5) & 15, t = e >> 9;
      const size_t row = (size_t)(bg + b) * T_ + t0 + t;
      const float dtv = delta_t[row];
      const float2 xv = *(const float2*)(x + row * F_ + f0);
      const float2 mv = *(const float2*)(m + row * F_ + f0);
      float gxa = __expf(gx0 * dtv);
      const float d0 = fmaf(mv.x, xv.x, (1.f - mv.x) * (gxa * xv.x + (1.f - gxa) * mi0));
      gxa = __expf(gx1 * dtv);
      const float d1 = fmaf(mv.y, xv.y, (1.f - mv.y) * (gxa * xv.y + (1.f - gxa) * mi1));
      const int sidx = t * 1024 + b * 64 + (((f0 >> 3) ^ (b & 7)) << 3) + (f0 & 7);
      *(unsigned*)(s_x + sidx) = packh2(d0, d1);
    }
    __syncthreads();

    AXLOAD(0);   // x-projections (+bias) for tc=0

    // ---- 16 recurrent steps ----
#pragma unroll 1
    for (int tc = 0; tc < HC; ++tc) {
      __syncthreads();   // (1) s_hd ready
      const int hbase = bl * 128;
      const f16x8 hb0 = *(const f16x8*)(s_hd + hbase + (((0  + g) ^ (bl & 7)) << 3));
      const f16x8 hb1 = *(const f16x8*)(s_hd + hbase + (((4  + g) ^ (bl & 7)) << 3));
      const f16x8 hb2 = *(const f16x8*)(s_hd + hbase + (((8  + g) ^ (bl & 7)) << 3));
      const f16x8 hb3 = *(const f16x8*)(s_hd + hbase + (((12 + g) ^ (bl & 7)) << 3));
      f32x4 az0 = axz[0], az1 = axz[1], ar0 = axr[0], ar1 = axr[1];
      f32x4 ah0 = axh[0], ah1 = axh[1];   // captured before AXLOAD overwrites
      az0 = MFMA(uzA[0][0], hb0, az0); az1 = MFMA(uzA[1][0], hb0, az1);
      ar0 = MFMA(urA[0][0], hb0, ar0); ar1 = MFMA(urA[1][0], hb0, ar1);
      az0 = MFMA(uzA[0][1], hb1, az0); az1 = MFMA(uzA[1][1], hb1, az1);
      ar0 = MFMA(urA[0][1], hb1, ar0); ar1 = MFMA(urA[1][1], hb1, ar1);
      az0 = MFMA(uzA[0][2], hb2, az0); az1 = MFMA(uzA[1][2], hb2, az1);
      ar0 = MFMA(urA[0][2], hb2, ar0); ar1 = MFMA(urA[1][2], hb2, ar1);
      az0 = MFMA(uzA[0][3], hb3, az0); az1 = MFMA(uzA[1][3], hb3, az1);
      ar0 = MFMA(urA[0][3], hb3, ar0); ar1 = MFMA(urA[1][3], hb3, ar1);
      // r sigmoid -> rh -> LDS (critical path)
      {
        uint2 w0, w1;
        w0.x = packh2(fast_sig(ar0[0]) * hdT[0][0], fast_sig(ar0[1]) * hdT[0][1]);
        w0.y = packh2(fast_sig(ar0[2]) * hdT[0][2], fast_sig(ar0[3]) * hdT[0][3]);
        w1.x = packh2(fast_sig(ar1[0]) * hdT[1][0], fast_sig(ar1[1]) * hdT[1][1]);
        w1.y = packh2(fast_sig(ar1[2]) * hdT[1][2], fast_sig(ar1[3]) * hdT[1][3]);
        *(uint2*)(s_rh + hw0) = w0;
        *(uint2*)(s_rh + hw1) = w1;
      }
      // off-path: z sigmoid, decay factors, next-step x-proj
#pragma unroll
      for (int r = 0; r < 4; ++r) { zz[0][r] = fast_sig(az0[r]); zz[1][r] = fast_sig(az1[r]); }
      const float dtb = s_dtn[tc * 16 + bl];
#pragma unroll
      for (int q = 0; q < 2; ++q)
#pragma unroll
        for (int r = 0; r < 4; ++r) ghn[q][r] = __expf(gam[q][r] * dtb);
      if (tc + 1 < HC) { AXLOAD(tc + 1); }
      __syncthreads();   // (2) s_rh ready
      const f16x8 rb0 = *(const f16x8*)(s_rh + hbase + (((0  + g) ^ (bl & 7)) << 3));
      const f16x8 rb1 = *(const f16x8*)(s_rh + hbase + (((4  + g) ^ (bl & 7)) << 3));
      const f16x8 rb2 = *(const f16x8*)(s_rh + hbase + (((8  + g) ^ (bl & 7)) << 3));
      const f16x8 rb3 = *(const f16x8*)(s_rh + hbase + (((12 + g) ^ (bl & 7)) << 3));
      ah0 = MFMA(uhA[0][0], rb0, ah0); ah1 = MFMA(uhA[1][0], rb0, ah1);
      ah0 = MFMA(uhA[0][1], rb1, ah0); ah1 = MFMA(uhA[1][1], rb1, ah1);
      ah0 = MFMA(uhA[0][2], rb2, ah0); ah1 = MFMA(uhA[1][2], rb2, ah1);
      ah0 = MFMA(uhA[0][3], rb3, ah0); ah1 = MFMA(uhA[1][3], rb3, ah1);
      // tanh, mix, state update + writes
      {
        float hn0[4], hn1[4];
#pragma unroll
        for (int r = 0; r < 4; ++r) {
          const float hh0 = fast_tanh(ah0[r]);
          hn0[r] = fmaf(zz[0][r], hh0 - hdT[0][r], hdT[0][r]);
          hdT[0][r] = ghn[0][r] * hn0[r];
          const float hh1 = fast_tanh(ah1[r]);
          hn1[r] = fmaf(zz[1][r], hh1 - hdT[1][r], hdT[1][r]);
          hdT[1][r] = ghn[1][r] * hn1[r];
        }
        uint2 hv0, hv1, hw0v, hw1v;
        hv0.x = packh2(hn0[0], hn0[1]); hv0.y = packh2(hn0[2], hn0[3]);
        hv1.x = packh2(hn1[0], hn1[1]); hv1.y = packh2(hn1[2], hn1[3]);
        *(uint2*)(s_hist + tc * 2048 + hw0) = hv0;
        *(uint2*)(s_hist + tc * 2048 + hw1) = hv1;
        hw0v.x = packh2(hdT[0][0], hdT[0][1]); hw0v.y = packh2(hdT[0][2], hdT[0][3]);
        hw1v.x = packh2(hdT[1][0], hdT[1][1]); hw1v.y = packh2(hdT[1][2], hdT[1][3]);
        *(uint2*)(s_hd + hw0) = hw0v;
        *(uint2*)(s_hd + hw1) = hw1v;
      }
    }
  }

  // ---- final flush ----
  __syncthreads();
  {
    const int t0p = T_ - HC;
#pragma unroll 1
    for (int i = 0; i < 16; ++i) {
      const int e = tid + 256 * i;
      const int ck = e & 15, b = (e >> 4) & 15, t = e >> 8;
      const int pck = (ck & 8) | ((ck ^ b) & 7);
      const f16x8 hv = *(const f16x8*)(s_hist + t * 2048 + b * 128 + pck * 8);
      float4 o0, o1;
      o0.x = (float)hv[0]; o0.y = (float)hv[1]; o0.z = (float)hv[2]; o0.w = (float)hv[3];
      o1.x = (float)hv[4]; o1.y = (float)hv[5]; o1.z = (float)hv[6]; o1.w = (float)hv[7];
      float* ob = out + ((size_t)(bg + b) * T_ + t0p + t) * U_ + ck * 8;
      *(float4*)ob = o0; *(float4*)(ob + 4) = o1;
    }
  }
}

extern "C" void kernel_launch(void* const* d_in, const int* in_sizes, int n_in,
                              void* d_out, int out_size, void* d_ws, size_t ws_size,
                              hipStream_t stream) {
  const float* x   = (const float*)d_in[0];
  const float* m   = (const float*)d_in[1];
  const float* dt  = (const float*)d_in[2];
  const float* Wz  = (const float*)d_in[3];
  const float* Uz  = (const float*)d_in[4];
  const float* bz  = (const float*)d_in[5];
  const float* Wr  = (const float*)d_in[6];
  const float* Ur  = (const float*)d_in[7];
  const float* br  = (const float*)d_in[8];
  const float* Wh  = (const float*)d_in[9];
  const float* Uh  = (const float*)d_in[10];
  const float* bh  = (const float*)d_in[11];
  const float* gxd = (const float*)d_in[12];
  const float* ghd = (const float*)d_in[13];
  const float* mi  = (const float*)d_in[14];

  grud_kernel<<<dim3(B_ / BPB), dim3(256), 0, stream>>>(
      x, m, dt, Wz, Uz, bz, Wr, Ur, br, Wh, Uh, bh, gxd, ghd, mi, (float*)d_out);
}

// Round 11
// 649.484 us; speedup vs baseline: 1.3358x; 1.3358x over previous
//
#include <hip/hip_runtime.h>

#define B_ 256
#define T_ 512
#define F_ 64
#define U_ 128

typedef _Float16 h2v __attribute__((ext_vector_type(2)));
union U32H2 { unsigned u; h2v h; };

__device__ __forceinline__ float fdot2(unsigned a, unsigned b, float c) {
  U32H2 x, y; x.u = a; y.u = b;
  return __builtin_amdgcn_fdot2(x.h, y.h, c, false);
}
__device__ __forceinline__ unsigned packh2(float a, float b) {
  U32H2 r; r.h[0] = (_Float16)a; r.h[1] = (_Float16)b; return r.u;
}
// lane-pair sum via quad_perm [1,0,3,2]; both lanes get the pair total.
__device__ __forceinline__ float pairsum(float v) {
  int t = __builtin_amdgcn_update_dpp(0, __float_as_int(v), 0xB1, 0xF, 0xF, true);
  return v + __int_as_float(t);
}
__device__ __forceinline__ float fast_sig(float x) {
  return __builtin_amdgcn_rcpf(1.0f + __expf(-x));
}
__device__ __forceinline__ float fast_tanh(float x) {
  return fmaf(-2.0f, __builtin_amdgcn_rcpf(1.0f + __expf(2.0f * x)), 1.0f);
}

#define D4(acc, Hv, Wr, o)                                        \
  acc = fdot2(Hv.x, Wr[(o)], acc);                                \
  acc = fdot2(Hv.y, Wr[(o) + 1], acc);                            \
  acc = fdot2(Hv.z, Wr[(o) + 2], acc);                            \
  acc = fdot2(Hv.w, Wr[(o) + 3], acc);

// x-projections (z,r,h) for step T from staged fp16 x
#define XPROJ(T, SX, AXZ, AXR, AXH) do {                          \
    const uint4* xp = (const uint4*)((SX) + (T) * F_ + 32 * p);   \
    float a0 = 0.f, a1 = 0.f, a2 = 0.f;                           \
    _Pragma("unroll") for (int q = 0; q < 4; ++q) {               \
      const uint4 Xv = xp[q];                                     \
      D4(a0, Xv, wz, 4 * q) D4(a1, Xv, wr, 4 * q)                 \
      D4(a2, Xv, wh, 4 * q)                                       \
    }                                                             \
    AXZ = a0; AXR = a1; AXH = a2;                                 \
  } while (0)

// window B recurrent dots for one batch: az, ar (reduced + bias)
#define BWIN(SHD, AXZ, AXR, AZ, AR) do {                          \
    const uint4* hp = (const uint4*)((SHD) + 64 * p);             \
    float a0 = AXZ, a1 = 0.f, r0 = AXR, r1 = 0.f;                 \
    _Pragma("unroll") for (int jj = 0; jj < 4; ++jj) {            \
      const uint4 Ha = hp[jj], Hb = hp[jj + 4];                   \
      D4(a0, Ha, uz, 4 * jj)  D4(a1, Hb, uz, 4 * jj + 16)         \
      D4(r0, Ha, ur, 4 * jj)  D4(r1, Hb, ur, 4 * jj + 16)         \
    }                                                             \
    AZ = pairsum(a0 + a1) + bzc;                                  \
    AR = pairsum(r0 + r1) + brc;                                  \
  } while (0)

// window C candidate dots for one batch
#define CWIN(SRH, AXH, AH) do {                                   \
    const uint4* rp = (const uint4*)((SRH) + 64 * p);             \
    float a0 = AXH, a1 = 0.f;                                     \
    _Pragma("unroll") for (int q = 0; q < 4; ++q) {               \
      const uint4 Ra = rp[q], Rb = rp[q + 4];                     \
      D4(a0, Ra, uh, 4 * q)  D4(a1, Rb, uh, 4 * q + 16)           \
    }                                                             \
    AH = pairsum(a0 + a1) + bhc;                                  \
  } while (0)

// chunk staging of decayed x (fp16) for one batch
#define XSTAGE(BIDX, SDT, SX) do {                                \
    _Pragma("unroll") for (int i = 0; i < 2; ++i) {               \
      const int e4 = tid + 256 * i;                               \
      const int t = e4 >> 4, f0 = (e4 & 15) << 2;                 \
      const float dtv = (SDT)[t0 + t];                            \
      const float4 xv  = *(const float4*)(x + (size_t)((BIDX) * T_ + t0 + t) * F_ + f0); \
      const float4 mv  = *(const float4*)(m + (size_t)((BIDX) * T_ + t0 + t) * F_ + f0); \
      const float4 gv  = *(const float4*)(s_gxf + f0);            \
      const float4 miv = *(const float4*)(s_mi + f0);             \
      float gx, d0, d1, d2, d3;                                   \
      gx = __expf(gv.x * dtv);                                    \
      d0 = fmaf(mv.x, xv.x, (1.0f - mv.x) * (gx * xv.x + (1.0f - gx) * miv.x)); \
      gx = __expf(gv.y * dtv);                                    \
      d1 = fmaf(mv.y, xv.y, (1.0f - mv.y) * (gx * xv.y + (1.0f - gx) * miv.y)); \
      gx = __expf(gv.z * dtv);                                    \
      d2 = fmaf(mv.z, xv.z, (1.0f - mv.z) * (gx * xv.z + (1.0f - gx) * miv.z)); \
      gx = __expf(gv.w * dtv);                                    \
      d3 = fmaf(mv.w, xv.w, (1.0f - mv.w) * (gx * xv.w + (1.0f - gx) * miv.w)); \
      uint2 px; px.x = packh2(d0, d1); px.y = packh2(d2, d3);     \
      *(uint2*)((SX) + 4 * e4) = px;                              \
    }                                                             \
  } while (0)

__global__ __launch_bounds__(256, 1)
__attribute__((amdgpu_waves_per_eu(1, 1)))
void grud_kernel(
    const float* __restrict__ x, const float* __restrict__ m,
    const float* __restrict__ delta_t,
    const float* __restrict__ Wz_, const float* __restrict__ Uz, const float* __restrict__ bz,
    const float* __restrict__ Wr_, const float* __restrict__ Ur, const float* __restrict__ br,
    const float* __restrict__ Wh_, const float* __restrict__ Uh, const float* __restrict__ bh,
    const float* __restrict__ gxd, const float* __restrict__ ghd,
    const float* __restrict__ mi,
    float* __restrict__ out)
{
  const int tid = threadIdx.x;
  const int b0  = 2 * blockIdx.x;      // this block's two batches
  const int b1  = b0 + 1;
  const int w   = tid >> 6;
  const int l   = tid & 63;
  const int c   = 32 * w + (l >> 1);   // owned output column
  const int p   = l & 1;               // k-half
  const bool ev = (p == 0);

  __shared__ float  s_dt0[520], s_dt1[520];
  __shared__ float  s_ghv0[32 * U_], s_ghv1[32 * U_];
  __shared__ float  s_hist0[32 * U_], s_hist1[32 * U_];
  __shared__ __align__(16) ushort s_x0[32 * F_], s_x1[32 * F_];
  __shared__ __align__(16) ushort s_hd0[U_], s_hd1[U_];
  __shared__ __align__(16) ushort s_rh0[U_], s_rh1[U_];
  __shared__ float  s_negg[U_], s_gxf[F_], s_mi[F_];

  // ---- weights into registers (shared by both batches) ----
  unsigned uz[32], ur[32], uh[32];
  unsigned wz[16], wr[16], wh[16];
#pragma unroll
  for (int j = 0; j < 32; ++j) {
    const int k0 = 64 * p + 2 * j;
    uz[j] = packh2(Uz[k0 * U_ + c], Uz[(k0 + 1) * U_ + c]);
    ur[j] = packh2(Ur[k0 * U_ + c], Ur[(k0 + 1) * U_ + c]);
    uh[j] = packh2(Uh[k0 * U_ + c], Uh[(k0 + 1) * U_ + c]);
  }
#pragma unroll
  for (int j = 0; j < 16; ++j) {
    const int f0 = 32 * p + 2 * j;
    wz[j] = packh2(Wz_[f0 * U_ + c], Wz_[(f0 + 1) * U_ + c]);
    wr[j] = packh2(Wr_[f0 * U_ + c], Wr_[(f0 + 1) * U_ + c]);
    wh[j] = packh2(Wh_[f0 * U_ + c], Wh_[(f0 + 1) * U_ + c]);
  }
  const float bzc = bz[c], brc = br[c], bhc = bh[c];

  // ---- one-time LDS tables ----
  {
    s_dt0[tid]       = delta_t[(size_t)b0 * T_ + tid];
    s_dt0[tid + 256] = delta_t[(size_t)b0 * T_ + tid + 256];
    s_dt1[tid]       = delta_t[(size_t)b1 * T_ + tid];
    s_dt1[tid + 256] = delta_t[(size_t)b1 * T_ + tid + 256];
    if (tid < 8) { s_dt0[512 + tid] = 0.0f; s_dt1[512 + tid] = 0.0f; }
    if (tid < U_) {
      s_negg[tid] = -fmaxf(ghd[tid], 0.0f);
      ((unsigned*)s_hd0)[tid >> 1] = 0u;
      ((unsigned*)s_hd1)[tid >> 1] = 0u;
    }
    if (tid < F_) { s_gxf[tid] = -fmaxf(gxd[tid], 0.0f); s_mi[tid] = mi[tid]; }
  }
  __syncthreads();

  float hd0 = 0.0f, hd1 = 0.0f;
  float axz0 = 0.f, axr0 = 0.f, axh0 = 0.f;
  float axz1 = 0.f, axr1 = 0.f, axh1 = 0.f;

  for (int t0 = 0; t0 < T_; t0 += 32) {
    // ======== chunk staging (bulk; only place with global loads) ========
    XSTAGE(b0, s_dt0, s_x0);
    XSTAGE(b1, s_dt1, s_x1);
    // decay tables: ghv[t][c] = exp(-g_c * dt[t0+t+1])
#pragma unroll
    for (int i = 0; i < 16; ++i) {
      const int e = tid + 256 * i;             // 0..4095
      const int t = e >> 7, cc = e & 127;
      s_ghv0[e] = __expf(s_negg[cc] * s_dt0[t0 + t + 1]);
      s_ghv1[e] = __expf(s_negg[cc] * s_dt1[t0 + t + 1]);
    }
    __syncthreads();

    // chunk prologue: x-projections for tc = 0, both batches
    XPROJ(0, s_x0, axz0, axr0, axh0);
    XPROJ(0, s_x1, axz1, axr1, axh1);

    // ======== 32 recurrent steps: LDS-only, dual-batch interleaved ========
#pragma unroll 1
    for (int tc = 0; tc < 32; ++tc) {
      // ---- window B: z, r for both batches ----
      float az0v, ar0v, az1v, ar1v;
      BWIN(s_hd0, axz0, axr0, az0v, ar0v);
      BWIN(s_hd1, axz1, axr1, az1v, ar1v);
      const float zg0 = fast_sig(az0v);
      const float rg0 = fast_sig(ar0v);
      const float zg1 = fast_sig(az1v);
      const float rg1 = fast_sig(ar1v);
      if (ev) {
        ((_Float16*)s_rh0)[c] = (_Float16)(rg0 * hd0);
        ((_Float16*)s_rh1)[c] = (_Float16)(rg1 * hd1);
      }
      __syncthreads();

      // ---- window C: candidate + update, both batches ----
      float ah0v, ah1v;
      CWIN(s_rh0, axh0, ah0v);
      CWIN(s_rh1, axh1, ah1v);
      if (tc < 31) {                       // next-step x-proj (latency filler)
        XPROJ(tc + 1, s_x0, axz0, axr0, axh0);
        XPROJ(tc + 1, s_x1, axz1, axr1, axh1);
      }
      const float hh0 = fast_tanh(ah0v);
      const float hh1 = fast_tanh(ah1v);
      const float hn0 = fmaf(zg0, hh0 - hd0, hd0);
      const float hn1 = fmaf(zg1, hh1 - hd1, hd1);
      if (ev) { s_hist0[tc * U_ + c] = hn0; s_hist1[tc * U_ + c] = hn1; }
      hd0 = s_ghv0[tc * U_ + c] * hn0;
      hd1 = s_ghv1[tc * U_ + c] * hn1;
      if (ev) {
        ((_Float16*)s_hd0)[c] = (_Float16)hd0;
        ((_Float16*)s_hd1)[c] = (_Float16)hd1;
      }
      __syncthreads();
    }

    // ======== flush chunk outputs (coalesced) ========
    {
      const float4* h40 = (const float4*)s_hist0;
      float4* o40 = (float4*)(out + (size_t)(b0 * T_ + t0) * U_);
#pragma unroll
      for (int i = 0; i < 4; ++i) o40[tid + 256 * i] = h40[tid + 256 * i];
      const float4* h41 = (const float4*)s_hist1;
      float4* o41 = (float4*)(out + (size_t)(b1 * T_ + t0) * U_);
#pragma unroll
      for (int i = 0; i < 4; ++i) o41[tid + 256 * i] = h41[tid + 256 * i];
    }
  }
}

extern "C" void kernel_launch(void* const* d_in, const int* in_sizes, int n_in,
                              void* d_out, int out_size, void* d_ws, size_t ws_size,
                              hipStream_t stream) {
  const float* x   = (const float*)d_in[0];
  const float* m   = (const float*)d_in[1];
  const float* dt  = (const float*)d_in[2];
  const float* Wz  = (const float*)d_in[3];
  const float* Uz  = (const float*)d_in[4];
  const float* bz  = (const float*)d_in[5];
  const float* Wr  = (const float*)d_in[6];
  const float* Ur  = (const float*)d_in[7];
  const float* br  = (const float*)d_in[8];
  const float* Wh  = (const float*)d_in[9];
  const float* Uh  = (const float*)d_in[10];
  const float* bh  = (const float*)d_in[11];
  const float* gxd = (const float*)d_in[12];
  const float* ghd = (const float*)d_in[13];
  const float* mi  = (const float*)d_in[14];

  grud_kernel<<<dim3(B_ / 2), dim3(256), 0, stream>>>(
      x, m, dt, Wz, Uz, bz, Wr, Ur, br, Wh, Uh, bh, gxd, ghd, mi, (float*)d_out);
}

// Round 12
// 409.359 us; speedup vs baseline: 2.1194x; 1.5866x over previous
//
#include <hip/hip_runtime.h>

#define B_ 256
#define T_ 512
#define F_ 64
#define U_ 128

typedef _Float16 h2v __attribute__((ext_vector_type(2)));
union U32H2 { unsigned u; h2v h; };

__device__ __forceinline__ float fdot2(unsigned a, unsigned b, float c) {
  U32H2 x, y; x.u = a; y.u = b;
  return __builtin_amdgcn_fdot2(x.h, y.h, c, false);
}
__device__ __forceinline__ unsigned packh2(float a, float b) {
  U32H2 r; r.h[0] = (_Float16)a; r.h[1] = (_Float16)b; return r.u;
}
// lane-pair sum via quad_perm [1,0,3,2]; both lanes get the pair total.
__device__ __forceinline__ float pairsum(float v) {
  int t = __builtin_amdgcn_update_dpp(0, __float_as_int(v), 0xB1, 0xF, 0xF, true);
  return v + __int_as_float(t);
}
__device__ __forceinline__ float fast_sig(float x) {
  return __builtin_amdgcn_rcpf(1.0f + __expf(-x));
}
__device__ __forceinline__ float fast_tanh(float x) {
  return fmaf(-2.0f, __builtin_amdgcn_rcpf(1.0f + __expf(2.0f * x)), 1.0f);
}

#define D4(acc, Hv, Wr, o)                                        \
  acc = fdot2(Hv.x, Wr[(o)], acc);                                \
  acc = fdot2(Hv.y, Wr[(o) + 1], acc);                            \
  acc = fdot2(Hv.z, Wr[(o) + 2], acc);                            \
  acc = fdot2(Hv.w, Wr[(o) + 3], acc);

__global__ __launch_bounds__(256, 1)
__attribute__((amdgpu_waves_per_eu(1, 1)))
void grud_kernel(
    const float* __restrict__ x, const float* __restrict__ m,
    const float* __restrict__ delta_t,
    const float* __restrict__ Wz_, const float* __restrict__ Uz, const float* __restrict__ bz,
    const float* __restrict__ Wr_, const float* __restrict__ Ur, const float* __restrict__ br,
    const float* __restrict__ Wh_, const float* __restrict__ Uh, const float* __restrict__ bh,
    const float* __restrict__ gxd, const float* __restrict__ ghd,
    const float* __restrict__ mi,
    float* __restrict__ out)
{
  const int tid = threadIdx.x;
  const int b   = blockIdx.x;
  const int w   = tid >> 6;           // wave 0..3
  const int l   = tid & 63;
  const int c   = 32 * w + (l >> 1);  // owned output column
  const int p   = l & 1;              // k-half
  const bool ev = (p == 0);

  __shared__ float  s_dt[520];
  __shared__ float  s_ghv[32 * U_];               // per-chunk decay factors
  __shared__ float  s_hist[32 * U_];              // per-chunk outputs (fp32)
  __shared__ __align__(16) ushort s_x16[32 * F_]; // per-chunk decayed x (fp16)
  __shared__ __align__(16) ushort s_hd16[U_];
  __shared__ __align__(16) ushort s_rh16[U_];
  __shared__ float  s_negg[U_];
  __shared__ float  s_gxf[F_];
  __shared__ float  s_mi[F_];

  // ---- weights into registers (fp16 pairs along k) ----
  unsigned uz[32], ur[32], uh[32];
  unsigned wz[16], wr[16], wh[16];
#pragma unroll
  for (int j = 0; j < 32; ++j) {
    const int k0 = 64 * p + 2 * j;
    uz[j] = packh2(Uz[k0 * U_ + c], Uz[(k0 + 1) * U_ + c]);
    ur[j] = packh2(Ur[k0 * U_ + c], Ur[(k0 + 1) * U_ + c]);
    uh[j] = packh2(Uh[k0 * U_ + c], Uh[(k0 + 1) * U_ + c]);
  }
#pragma unroll
  for (int j = 0; j < 16; ++j) {
    const int f0 = 32 * p + 2 * j;
    wz[j] = packh2(Wz_[f0 * U_ + c], Wz_[(f0 + 1) * U_ + c]);
    wr[j] = packh2(Wr_[f0 * U_ + c], Wr_[(f0 + 1) * U_ + c]);
    wh[j] = packh2(Wh_[f0 * U_ + c], Wh_[(f0 + 1) * U_ + c]);
  }
  const float bzc = bz[c], brc = br[c], bhc = bh[c];

  // ---- one-time LDS tables ----
  {
    const float* dtb = delta_t + (size_t)b * T_;
    s_dt[tid]       = dtb[tid];
    s_dt[tid + 256] = dtb[tid + 256];
    if (tid < 8)   s_dt[512 + tid] = 0.0f;
    if (tid < U_)  { s_negg[tid] = -fmaxf(ghd[tid], 0.0f); ((unsigned*)s_hd16)[tid >> 1] = 0u; }
    if (tid < F_)  { s_gxf[tid] = -fmaxf(gxd[tid], 0.0f); s_mi[tid] = mi[tid]; }
  }
  __syncthreads();

  float hd_own = 0.0f;
  float axz = 0.f, axr = 0.f, axh = 0.f;

  for (int t0 = 0; t0 < T_; t0 += 32) {
    // ======== chunk staging (bulk; only place with global loads) ========
#pragma unroll
    for (int i = 0; i < 2; ++i) {
      const int e4 = tid + 256 * i;            // 0..511 quad-groups
      const int t = e4 >> 4, f0 = (e4 & 15) << 2;
      const float dtv = s_dt[t0 + t];
      const float4 xv  = *(const float4*)(x + (size_t)(b * T_ + t0 + t) * F_ + f0);
      const float4 mv  = *(const float4*)(m + (size_t)(b * T_ + t0 + t) * F_ + f0);
      const float4 gv  = *(const float4*)(s_gxf + f0);
      const float4 miv = *(const float4*)(s_mi + f0);
      float gx, d0, d1, d2, d3;
      gx = __expf(gv.x * dtv);
      d0 = fmaf(mv.x, xv.x, (1.0f - mv.x) * (gx * xv.x + (1.0f - gx) * miv.x));
      gx = __expf(gv.y * dtv);
      d1 = fmaf(mv.y, xv.y, (1.0f - mv.y) * (gx * xv.y + (1.0f - gx) * miv.y));
      gx = __expf(gv.z * dtv);
      d2 = fmaf(mv.z, xv.z, (1.0f - mv.z) * (gx * xv.z + (1.0f - gx) * miv.z));
      gx = __expf(gv.w * dtv);
      d3 = fmaf(mv.w, xv.w, (1.0f - mv.w) * (gx * xv.w + (1.0f - gx) * miv.w));
      uint2 px; px.x = packh2(d0, d1); px.y = packh2(d2, d3);
      *(uint2*)(s_x16 + 4 * e4) = px;
    }
    // decay table for this chunk: ghv[t][c] = exp(-g_c * dt[t0+t+1])
#pragma unroll
    for (int i = 0; i < 16; ++i) {
      const int e = tid + 256 * i;             // 0..4095
      const int t = e >> 7, cc = e & 127;
      s_ghv[e] = __expf(s_negg[cc] * s_dt[t0 + t + 1]);
    }
    __syncthreads();

    // chunk prologue: x-projections for tc = 0
    {
      const uint4* xp = (const uint4*)(s_x16 + 32 * p);
      float a0 = 0.f, a1 = 0.f, a2 = 0.f;
#pragma unroll
      for (int q = 0; q < 4; ++q) {
        const uint4 Xv = xp[q];
        D4(a0, Xv, wz, 4 * q) D4(a1, Xv, wr, 4 * q) D4(a2, Xv, wh, 4 * q)
      }
      axz = a0; axr = a1; axh = a2;
    }

    // ======== 32 recurrent steps: LDS-only ========
#pragma unroll 1
    for (int tc = 0; tc < 32; ++tc) {
      // ---- window B ----
      // chunk-static decay factor: issued early, consumed in window C (off-path)
      const float ghv = s_ghv[tc * U_ + c];
      const uint4* hp = (const uint4*)(s_hd16 + 64 * p);
      // r-gate FIRST (it feeds s_rh16 -> critical path)
      float ar0 = axr, ar1 = 0.f;
#pragma unroll
      for (int jj = 0; jj < 4; ++jj) {
        const uint4 Ha = hp[jj], Hb = hp[jj + 4];
        D4(ar0, Ha, ur, 4 * jj)  D4(ar1, Hb, ur, 4 * jj + 16)
      }
      const float r = fast_sig(pairsum(ar0 + ar1) + brc);
      if (ev) ((_Float16*)s_rh16)[c] = (_Float16)(r * hd_own);
      // z-gate dots AFTER the rh write (absorb barrier skew)
      float az0 = axz, az1 = 0.f;
#pragma unroll
      for (int jj = 0; jj < 4; ++jj) {
        const uint4 Ha = hp[jj], Hb = hp[jj + 4];
        D4(az0, Ha, uz, 4 * jj)  D4(az1, Hb, uz, 4 * jj + 16)
      }
      const float z = fast_sig(pairsum(az0 + az1) + bzc);
      // next-step z x-projection (filler)
      if (tc < 31) {
        const uint4* xp = (const uint4*)(s_x16 + (tc + 1) * F_ + 32 * p);
        float a0 = 0.f;
#pragma unroll
        for (int q = 0; q < 4; ++q) { const uint4 Xv = xp[q]; D4(a0, Xv, wz, 4 * q) }
        axz = a0;
      }
      __syncthreads();

      // ---- window C ----
      const uint4* rp = (const uint4*)(s_rh16 + 64 * p);
      float ah0 = axh, ah1 = 0.f;
#pragma unroll
      for (int q = 0; q < 4; ++q) {
        const uint4 Ra = rp[q], Rb = rp[q + 4];
        D4(ah0, Ra, uh, 4 * q)  D4(ah1, Rb, uh, 4 * q + 16)
      }
      const float ah = pairsum(ah0 + ah1) + bhc;
      const float hh = fast_tanh(ah);
      const float hn = fmaf(z, hh - hd_own, hd_own);
      hd_own = ghv * hn;                       // ghv preloaded in window B
      if (ev) ((_Float16*)s_hd16)[c] = (_Float16)hd_own;  // unblock others ASAP
      // filler: next-step r/h x-projections, then hist write
      if (tc < 31) {
        const uint4* xp = (const uint4*)(s_x16 + (tc + 1) * F_ + 32 * p);
        float a1 = 0.f, a2 = 0.f;
#pragma unroll
        for (int q = 0; q < 4; ++q) {
          const uint4 Xv = xp[q];
          D4(a1, Xv, wr, 4 * q) D4(a2, Xv, wh, 4 * q)
        }
        axr = a1; axh = a2;
      }
      if (ev) s_hist[tc * U_ + c] = hn;
      __syncthreads();
    }

    // ======== flush chunk outputs (coalesced) ========
    {
      const float4* h4 = (const float4*)s_hist;
      float4* o4 = (float4*)(out + (size_t)(b * T_ + t0) * U_);
#pragma unroll
      for (int i = 0; i < 4; ++i) o4[tid + 256 * i] = h4[tid + 256 * i];
    }
  }
}

extern "C" void kernel_launch(void* const* d_in, const int* in_sizes, int n_in,
                              void* d_out, int out_size, void* d_ws, size_t ws_size,
                              hipStream_t stream) {
  const float* x   = (const float*)d_in[0];
  const float* m   = (const float*)d_in[1];
  const float* dt  = (const float*)d_in[2];
  const float* Wz  = (const float*)d_in[3];
  const float* Uz  = (const float*)d_in[4];
  const float* bz  = (const float*)d_in[5];
  const float* Wr  = (const float*)d_in[6];
  const float* Ur  = (const float*)d_in[7];
  const float* br  = (const float*)d_in[8];
  const float* Wh  = (const float*)d_in[9];
  const float* Uh  = (const float*)d_in[10];
  const float* bh  = (const float*)d_in[11];
  const float* gxd = (const float*)d_in[12];
  const float* ghd = (const float*)d_in[13];
  const float* mi  = (const float*)d_in[14];

  grud_kernel<<<dim3(B_), dim3(256), 0, stream>>>(
      x, m, dt, Wz, Uz, bz, Wr, Ur, br, Wh, Uh, bh, gxd, ghd, mi, (float*)d_out);
}

// Round 13
// 356.353 us; speedup vs baseline: 2.4347x; 1.1487x over previous
//
#include <hip/hip_runtime.h>

#define B_ 256
#define T_ 512
#define F_ 64
#define U_ 128

typedef _Float16 h2v __attribute__((ext_vector_type(2)));
union U32H2 { unsigned u; h2v h; };

__device__ __forceinline__ float fdot2(unsigned a, unsigned b, float c) {
  U32H2 x, y; x.u = a; y.u = b;
  return __builtin_amdgcn_fdot2(x.h, y.h, c, false);
}
__device__ __forceinline__ unsigned packh2(float a, float b) {
  U32H2 r; r.h[0] = (_Float16)a; r.h[1] = (_Float16)b; return r.u;
}
// sum over each aligned quad of lanes (kg = lane&3); all 4 lanes get the total.
__device__ __forceinline__ float red4(float v) {
  int t = __builtin_amdgcn_update_dpp(0, __float_as_int(v), 0xB1, 0xF, 0xF, true); // [1,0,3,2]
  v += __int_as_float(t);
  t = __builtin_amdgcn_update_dpp(0, __float_as_int(v), 0x4E, 0xF, 0xF, true);     // [2,3,0,1]
  v += __int_as_float(t);
  return v;
}
__device__ __forceinline__ float fast_sig(float x) {
  return __builtin_amdgcn_rcpf(1.0f + __expf(-x));
}
__device__ __forceinline__ float fast_tanh(float x) {
  return fmaf(-2.0f, __builtin_amdgcn_rcpf(1.0f + __expf(2.0f * x)), 1.0f);
}

#define D4(acc, Hv, Wr, o)                                        \
  acc = fdot2(Hv.x, Wr[(o)], acc);                                \
  acc = fdot2(Hv.y, Wr[(o) + 1], acc);                            \
  acc = fdot2(Hv.z, Wr[(o) + 2], acc);                            \
  acc = fdot2(Hv.w, Wr[(o) + 3], acc);

__global__ __launch_bounds__(256, 1)
__attribute__((amdgpu_waves_per_eu(1, 1)))
void grud_kernel(
    const float* __restrict__ x, const float* __restrict__ m,
    const float* __restrict__ delta_t,
    const float* __restrict__ Wz_, const float* __restrict__ Uz, const float* __restrict__ bz,
    const float* __restrict__ Wr_, const float* __restrict__ Ur, const float* __restrict__ br,
    const float* __restrict__ Wh_, const float* __restrict__ Uh, const float* __restrict__ bh,
    const float* __restrict__ gxd, const float* __restrict__ ghd,
    const float* __restrict__ mi,
    float* __restrict__ out)
{
  const int tid = threadIdx.x;
  const int b   = blockIdx.x;
  const int kg  = tid & 3;     // k-group: k in [32kg, 32kg+32); f in [16kg, 16kg+16)
  const int cp  = tid >> 2;    // column pair: cols {2cp, 2cp+1}
  const int c0  = 2 * cp;
  const bool wr_lane = (kg == 0);

  __shared__ float  s_dt[520];
  __shared__ float  s_ghv[32 * U_];               // per-chunk decay factors
  __shared__ float  s_hist[32 * U_];              // per-chunk outputs (fp32)
  __shared__ __align__(16) ushort s_x16[32 * F_]; // per-chunk decayed x (fp16)
  __shared__ __align__(16) ushort s_hd16[U_];
  __shared__ __align__(16) ushort s_rh16[U_];
  __shared__ float  s_negg[U_];
  __shared__ float  s_gxf[F_];
  __shared__ float  s_mi[F_];

  // ---- weights into registers (fp16 pairs along k); [0..16)=col0, [16..32)=col1 ----
  unsigned uz[32], ur[32], uh[32];
  unsigned wz[16], wr[16], wh[16];   // [0..8)=col0, [8..16)=col1
#pragma unroll
  for (int j = 0; j < 16; ++j) {
    const int k0 = 32 * kg + 2 * j;
    uz[j]      = packh2(Uz[k0 * U_ + c0],     Uz[(k0 + 1) * U_ + c0]);
    uz[16 + j] = packh2(Uz[k0 * U_ + c0 + 1], Uz[(k0 + 1) * U_ + c0 + 1]);
    ur[j]      = packh2(Ur[k0 * U_ + c0],     Ur[(k0 + 1) * U_ + c0]);
    ur[16 + j] = packh2(Ur[k0 * U_ + c0 + 1], Ur[(k0 + 1) * U_ + c0 + 1]);
    uh[j]      = packh2(Uh[k0 * U_ + c0],     Uh[(k0 + 1) * U_ + c0]);
    uh[16 + j] = packh2(Uh[k0 * U_ + c0 + 1], Uh[(k0 + 1) * U_ + c0 + 1]);
  }
#pragma unroll
  for (int j = 0; j < 8; ++j) {
    const int f0 = 16 * kg + 2 * j;
    wz[j]     = packh2(Wz_[f0 * U_ + c0],     Wz_[(f0 + 1) * U_ + c0]);
    wz[8 + j] = packh2(Wz_[f0 * U_ + c0 + 1], Wz_[(f0 + 1) * U_ + c0 + 1]);
    wr[j]     = packh2(Wr_[f0 * U_ + c0],     Wr_[(f0 + 1) * U_ + c0]);
    wr[8 + j] = packh2(Wr_[f0 * U_ + c0 + 1], Wr_[(f0 + 1) * U_ + c0 + 1]);
    wh[j]     = packh2(Wh_[f0 * U_ + c0],     Wh_[(f0 + 1) * U_ + c0]);
    wh[8 + j] = packh2(Wh_[f0 * U_ + c0 + 1], Wh_[(f0 + 1) * U_ + c0 + 1]);
  }
  const float bz0 = bz[c0], bz1 = bz[c0 + 1];
  const float br0 = br[c0], br1 = br[c0 + 1];
  const float bh0 = bh[c0], bh1 = bh[c0 + 1];

  // ---- one-time LDS tables ----
  {
    const float* dtb = delta_t + (size_t)b * T_;
    s_dt[tid]       = dtb[tid];
    s_dt[tid + 256] = dtb[tid + 256];
    if (tid < 8)   s_dt[512 + tid] = 0.0f;
    if (tid < U_)  { s_negg[tid] = -fmaxf(ghd[tid], 0.0f); ((unsigned*)s_hd16)[tid >> 1] = 0u; }
    if (tid < F_)  { s_gxf[tid] = -fmaxf(gxd[tid], 0.0f); s_mi[tid] = mi[tid]; }
  }
  __syncthreads();

  float hd0 = 0.0f, hd1 = 0.0f;                       // own columns' h_dec (fp32)
  float axz0 = 0.f, axz1 = 0.f, axr0 = 0.f, axr1 = 0.f, axh0 = 0.f, axh1 = 0.f;

  for (int t0 = 0; t0 < T_; t0 += 32) {
    // ======== chunk staging (bulk; only place with global loads) ========
#pragma unroll
    for (int i = 0; i < 2; ++i) {
      const int e4 = tid + 256 * i;            // 0..511 quad-groups
      const int t = e4 >> 4, f0 = (e4 & 15) << 2;
      const float dtv = s_dt[t0 + t];
      const float4 xv  = *(const float4*)(x + (size_t)(b * T_ + t0 + t) * F_ + f0);
      const float4 mv  = *(const float4*)(m + (size_t)(b * T_ + t0 + t) * F_ + f0);
      const float4 gv  = *(const float4*)(s_gxf + f0);
      const float4 miv = *(const float4*)(s_mi + f0);
      float gx, d0, d1, d2, d3;
      gx = __expf(gv.x * dtv);
      d0 = fmaf(mv.x, xv.x, (1.0f - mv.x) * (gx * xv.x + (1.0f - gx) * miv.x));
      gx = __expf(gv.y * dtv);
      d1 = fmaf(mv.y, xv.y, (1.0f - mv.y) * (gx * xv.y + (1.0f - gx) * miv.y));
      gx = __expf(gv.z * dtv);
      d2 = fmaf(mv.z, xv.z, (1.0f - mv.z) * (gx * xv.z + (1.0f - gx) * miv.z));
      gx = __expf(gv.w * dtv);
      d3 = fmaf(mv.w, xv.w, (1.0f - mv.w) * (gx * xv.w + (1.0f - gx) * miv.w));
      uint2 px; px.x = packh2(d0, d1); px.y = packh2(d2, d3);
      *(uint2*)(s_x16 + 4 * e4) = px;
    }
    // decay table for this chunk: ghv[t][c] = exp(-g_c * dt[t0+t+1])
#pragma unroll
    for (int i = 0; i < 16; ++i) {
      const int e = tid + 256 * i;             // 0..4095
      const int t = e >> 7, cc = e & 127;
      s_ghv[e] = __expf(s_negg[cc] * s_dt[t0 + t + 1]);
    }
    __syncthreads();

    // chunk prologue: x-projections for tc = 0 (both columns, all 3 gates)
    {
      const uint4* xp = (const uint4*)(s_x16 + 16 * kg);
      float a0 = 0.f, a1 = 0.f, a2 = 0.f, a3 = 0.f, a4 = 0.f, a5 = 0.f;
#pragma unroll
      for (int q = 0; q < 2; ++q) {
        const uint4 Xv = xp[q];
        D4(a0, Xv, wz, 4 * q)  D4(a1, Xv, wz, 8 + 4 * q)
        D4(a2, Xv, wr, 4 * q)  D4(a3, Xv, wr, 8 + 4 * q)
        D4(a4, Xv, wh, 4 * q)  D4(a5, Xv, wh, 8 + 4 * q)
      }
      axz0 = a0; axz1 = a1; axr0 = a2; axr1 = a3; axh0 = a4; axh1 = a5;
    }

    // ======== 32 recurrent steps: LDS-only ========
#pragma unroll 1
    for (int tc = 0; tc < 32; ++tc) {
      // ---- window B: z, r (shared h reads, reused for both columns) ----
      const uint4* hp = (const uint4*)(s_hd16 + 32 * kg);
      float az0 = axz0, az1 = axz1, ar0 = axr0, ar1 = axr1;
#pragma unroll
      for (int j = 0; j < 4; ++j) {
        const uint4 Hv = hp[j];
        D4(az0, Hv, uz, 4 * j)  D4(az1, Hv, uz, 16 + 4 * j)
        D4(ar0, Hv, ur, 4 * j)  D4(ar1, Hv, ur, 16 + 4 * j)
      }
      const float z0 = fast_sig(red4(az0) + bz0);
      const float z1 = fast_sig(red4(az1) + bz1);
      const float r0 = fast_sig(red4(ar0) + br0);
      const float r1 = fast_sig(red4(ar1) + br1);
      if (wr_lane) ((unsigned*)s_rh16)[cp] = packh2(r0 * hd0, r1 * hd1);
      __syncthreads();

      // ---- window C: candidate + update (+ next-step x-proj as filler) ----
      const float2 ghv = ((const float2*)s_ghv)[tc * 64 + cp];
      const uint4* rp = (const uint4*)(s_rh16 + 32 * kg);
      float ah0 = axh0, ah1 = axh1;
#pragma unroll
      for (int j = 0; j < 4; ++j) {
        const uint4 Rv = rp[j];
        D4(ah0, Rv, uh, 4 * j)  D4(ah1, Rv, uh, 16 + 4 * j)
      }
      if (tc < 31) {
        const uint4* xp = (const uint4*)(s_x16 + (tc + 1) * F_ + 16 * kg);
        float a0 = 0.f, a1 = 0.f, a2 = 0.f, a3 = 0.f, a4 = 0.f, a5 = 0.f;
#pragma unroll
        for (int q = 0; q < 2; ++q) {
          const uint4 Xv = xp[q];
          D4(a0, Xv, wz, 4 * q)  D4(a1, Xv, wz, 8 + 4 * q)
          D4(a2, Xv, wr, 4 * q)  D4(a3, Xv, wr, 8 + 4 * q)
          D4(a4, Xv, wh, 4 * q)  D4(a5, Xv, wh, 8 + 4 * q)
        }
        axz0 = a0; axz1 = a1; axr0 = a2; axr1 = a3; axh0 = a4; axh1 = a5;
      }
      const float hh0 = fast_tanh(red4(ah0) + bh0);
      const float hh1 = fast_tanh(red4(ah1) + bh1);
      const float hn0 = fmaf(z0, hh0 - hd0, hd0);
      const float hn1 = fmaf(z1, hh1 - hd1, hd1);
      hd0 = ghv.x * hn0;
      hd1 = ghv.y * hn1;
      if (wr_lane) {
        ((float2*)s_hist)[tc * 64 + cp] = make_float2(hn0, hn1);
        ((unsigned*)s_hd16)[cp] = packh2(hd0, hd1);
      }
      __syncthreads();
    }

    // ======== flush chunk outputs (coalesced) ========
    {
      const float4* h4 = (const float4*)s_hist;
      float4* o4 = (float4*)(out + (size_t)(b * T_ + t0) * U_);
#pragma unroll
      for (int i = 0; i < 4; ++i) o4[tid + 256 * i] = h4[tid + 256 * i];
    }
  }
}

extern "C" void kernel_launch(void* const* d_in, const int* in_sizes, int n_in,
                              void* d_out, int out_size, void* d_ws, size_t ws_size,
                              hipStream_t stream) {
  const float* x   = (const float*)d_in[0];
  const float* m   = (const float*)d_in[1];
  const float* dt  = (const float*)d_in[2];
  const float* Wz  = (const float*)d_in[3];
  const float* Uz  = (const float*)d_in[4];
  const float* bz  = (const float*)d_in[5];
  const float* Wr  = (const float*)d_in[6];
  const float* Ur  = (const float*)d_in[7];
  const float* br  = (const float*)d_in[8];
  const float* Wh  = (const float*)d_in[9];
  const float* Uh  = (const float*)d_in[10];
  const float* bh  = (const float*)d_in[11];
  const float* gxd = (const float*)d_in[12];
  const float* ghd = (const float*)d_in[13];
  const float* mi  = (const float*)d_in[14];

  grud_kernel<<<dim3(B_), dim3(256), 0, stream>>>(
      x, m, dt, Wz, Uz, bz, Wr, Ur, br, Wh, Uh, bh, gxd, ghd, mi, (float*)d_out);
}